// Round 9
// baseline (196.312 us; speedup 1.0000x reference)
//
#include <hip/hip_runtime.h>

// NIGnet: X -> 64x [Y = X@W.T + b; X = (tanh(Y)+Y)/2] -> X@fW.T -> L2 normalize.
// Working HW model (fit R1/R4-R8): separate trans pipe, v_exp/v_rcp ~ 17.5 cyc
// per wave64 op, overlapped with main pipe (full-rate = 2 cyc). R5 & R8 both sit
// at 35-36 cyc/value == 2 trans x 17.5, invariant to fma count => trans-bound.
// R9: halve rcp count via 2-way batched reciprocal over the two components of
// each point (shallow deps: only ONE mul after the rcp, unlike R7's 4-deep tree):
//   Yp  = (W/2)@s + C*(b+1)        (2 fma)     state s = 2C*x
//   Yc  = min(Yp, 63)              (1 min)     keeps d,P finite; r there ~5e-20
//   E   = exp2(Yc)                 (1 trans)
//   d   = fma(2^-C, E, 1)          (1 fma)     = e^{2y}+1, d in [1, 1.25e18]
//   P   = d0*d1; R = rcp(P)        (0.5 mul + 0.5 trans per value)
//   r0  = R*d1; r1 = R*d0          (1 mul)     r = 1/d exactly to ~1e-7 rel
//   s'  = fma(-2C, r, Yp)          (1 fma)     full residual update
// Mix: 6.5 full + 1.5 trans /value. Trans pipe: 1.5*17.5 = 26 cyc vs R5's 35.

#define KPT 8          // points per thread (4 float4 chunks)
#define BLOCK 256

__global__ __launch_bounds__(BLOCK, 8) void nig_kernel(
    const float* __restrict__ X_in,
    const float* __restrict__ Ws,    // [L,2,2] row-major
    const float* __restrict__ bs,    // [L,2]
    const float* __restrict__ fW,    // [2,2]
    float* __restrict__ out,
    int M,                           // float4 chunks = N/2
    int L)
{
    const int tid = blockIdx.x * blockDim.x + threadIdx.x;
    const int nthreads = gridDim.x * blockDim.x;
    const float4* __restrict__ in4 = (const float4*)X_in;
    float4* __restrict__ out4 = (float4*)out;

    const float C    = 2.8853900817779268f;    // 2*log2(e)
    const float twoC = 5.7707801635558537f;    // 2C
    const float n2C  = -5.7707801635558537f;   // -2C
    const float kE   = 0.13533528323661270f;   // 2^-C = e^-2
    const float YCL  = 63.0f;                  // exp2(63)*kE ~ 1.25e18; P <= 1.6e36

    // State s = 2C * x (final L2-normalize cancels the uniform scale).
    float s0[KPT], s1[KPT];
    int idx[KPT / 2]; bool ok[KPT / 2];
    #pragma unroll
    for (int j = 0; j < KPT / 2; ++j) {
        idx[j] = tid + j * nthreads;
        ok[j] = idx[j] < M;
        float4 v = ok[j] ? in4[idx[j]] : make_float4(0.f, 0.f, 0.f, 0.f);
        s0[2 * j]     = v.x * twoC; s1[2 * j]     = v.y * twoC;
        s0[2 * j + 1] = v.z * twoC; s1[2 * j + 1] = v.w * twoC;
    }

    float4 w = ((const float4*)Ws)[0];
    float2 b = ((const float2*)bs)[0];

    for (int l = 0; l < L; ++l) {
        const int ln = (l + 1 < L) ? (l + 1) : l;
        float4 wn = ((const float4*)Ws)[ln];   // prefetch next layer (s_load)
        float2 bn = ((const float2*)bs)[ln];

        // Uniform per-layer transforms (amortized over 16 values).
        const float hx = 0.5f * w.x, hy = 0.5f * w.y;
        const float hz = 0.5f * w.z, hw = 0.5f * w.w;
        const float cb0 = C * (b.x + 1.0f);
        const float cb1 = C * (b.y + 1.0f);

        #pragma unroll
        for (int k = 0; k < KPT; ++k) {
            float Yp0 = fmaf(hx, s0[k], fmaf(hy, s1[k], cb0));
            float Yp1 = fmaf(hz, s0[k], fmaf(hw, s1[k], cb1));
            float E0 = __builtin_amdgcn_exp2f(fminf(Yp0, YCL));
            float E1 = __builtin_amdgcn_exp2f(fminf(Yp1, YCL));
            float d0 = fmaf(kE, E0, 1.0f);     // e^{2y}+1 in [1, 1.25e18]
            float d1 = fmaf(kE, E1, 1.0f);
            float P  = d0 * d1;                // <= 1.6e36, no overflow
            float R  = __builtin_amdgcn_rcpf(P);
            float r0 = R * d1;                 // = 1/d0
            float r1 = R * d0;                 // = 1/d1
            s0[k] = fmaf(n2C, r0, Yp0);        // s' = Yp - 2C*r
            s1[k] = fmaf(n2C, r1, Yp1);
        }
        w = wn; b = bn;
    }

    // Final linear + L2 normalize (uniform scale 2C cancels).
    const float g0 = fW[0], g1 = fW[1], g2 = fW[2], g3 = fW[3];

    #pragma unroll
    for (int j = 0; j < KPT / 2; ++j) {
        if (!ok[j]) continue;
        float4 o;
        #pragma unroll
        for (int h = 0; h < 2; ++h) {
            const int k = 2 * j + h;
            float z0 = fmaf(g0, s0[k], g1 * s1[k]);
            float z1 = fmaf(g2, s0[k], g3 * s1[k]);
            float s  = fmaf(z0, z0, z1 * z1);
            float n  = __builtin_amdgcn_sqrtf(s);
            float iv = __builtin_amdgcn_rcpf(fmaxf(n, 1e-12f));
            if (h == 0) { o.x = z0 * iv; o.y = z1 * iv; }
            else        { o.z = z0 * iv; o.w = z1 * iv; }
        }
        out4[idx[j]] = o;
    }
}

extern "C" void kernel_launch(void* const* d_in, const int* in_sizes, int n_in,
                              void* d_out, int out_size, void* d_ws, size_t ws_size,
                              hipStream_t stream) {
    // 0=T(unused), 1=closed_manifold [N,2], 2=Ws [L,2,2], 3=bs [L,2], 4=final_W [2,2]
    const float* X  = (const float*)d_in[1];
    const float* Ws = (const float*)d_in[2];
    const float* bs = (const float*)d_in[3];
    const float* fW = (const float*)d_in[4];
    float* out = (float*)d_out;

    const int L = in_sizes[2] / 4;
    const int M = in_sizes[1] / 4;
    const int threads = (M + (KPT / 2) - 1) / (KPT / 2);
    const int grid = (threads + BLOCK - 1) / BLOCK;

    nig_kernel<<<grid, BLOCK, 0, stream>>>(X, Ws, bs, fW, out, M, L);
}

// Round 10
// 189.190 us; speedup vs baseline: 1.0376x; 1.0376x over previous
//
#include <hip/hip_runtime.h>

// NIGnet: X -> 64x [Y = X@W.T + b; X = (tanh(Y)+Y)/2] -> X@fW.T -> L2 normalize.
// FINAL (revert to R5, the measured optimum: 119.5 us dispatch).
// Session calibration (R1-R9, MI355X gfx950):
//  - The 5-full-rate + 2-trans per-value mix (2 fma linear, exp2, +1, rcp, 2 fma
//    update with state pre-scaled by C = 2*log2(e)) is the measured optimum.
//  - Invariant to ILP width (KPT 8 vs 16), occupancy (8 vs 4 waves/SIMD),
//    prefetch depth (1 vs 2), phase-split vs tight scheduling: 119.5-122.4 us.
//  - Every trans-reduction trade regressed: 8-way batched rcp 148 us, 2-way
//    batched rcp 130 us, poly 1/(1+q) 163 us, 6-instr fold 123 us.
//  - Issue floor for this mix at quarter-rate trans and sustained ~1.85 GHz
//    VALU-dense clock is ~116 us => measured 119.5 is at the roofline.

#define KPT 8          // points per thread (4 float4 chunks)
#define BLOCK 256

__global__ __launch_bounds__(BLOCK, 8) void nig_kernel(
    const float* __restrict__ X_in,
    const float* __restrict__ Ws,    // [L,2,2] row-major
    const float* __restrict__ bs,    // [L,2]
    const float* __restrict__ fW,    // [2,2]
    float* __restrict__ out,
    int M,                           // float4 chunks = N/2
    int L)
{
    const int tid = blockIdx.x * blockDim.x + threadIdx.x;
    const int nthreads = gridDim.x * blockDim.x;
    const float4* __restrict__ in4 = (const float4*)X_in;
    float4* __restrict__ out4 = (float4*)out;

    const float C     = 2.8853900817779268f;   // 2*log2(e)
    const float halfC = 1.4426950408889634f;   // C/2

    float u0[KPT], u1[KPT];
    int idx[KPT / 2]; bool ok[KPT / 2];
    #pragma unroll
    for (int j = 0; j < KPT / 2; ++j) {
        idx[j] = tid + j * nthreads;
        ok[j] = idx[j] < M;
        float4 v = ok[j] ? in4[idx[j]] : make_float4(0.f, 0.f, 0.f, 0.f);
        u0[2 * j]     = v.x * C; u1[2 * j]     = v.y * C;
        u0[2 * j + 1] = v.z * C; u1[2 * j + 1] = v.w * C;
    }

    float4 w = ((const float4*)Ws)[0];
    float2 b = ((const float2*)bs)[0];

    float y0[KPT], y1[KPT];    // C*(Wx+b)
    float d0[KPT], d1[KPT];    // exp2(y)+1

    #pragma unroll 2
    for (int l = 0; l < L; ++l) {
        const int ln = (l + 1 < L) ? (l + 1) : l;
        float4 wn = ((const float4*)Ws)[ln];   // prefetch next layer (s_load)
        float2 bn = ((const float2*)bs)[ln];

        const float cb0 = C * b.x;
        const float cb1 = C * b.y;

        // Phase 1: all linears (16 indep fma chains of 2)
        #pragma unroll
        for (int k = 0; k < KPT; ++k) {
            y0[k] = fmaf(w.x, u0[k], fmaf(w.y, u1[k], cb0));
            y1[k] = fmaf(w.z, u0[k], fmaf(w.w, u1[k], cb1));
        }
        // Phase 2: all 16 exps back-to-back into the trans pipe
        #pragma unroll
        for (int k = 0; k < KPT; ++k) {
            d0[k] = __builtin_amdgcn_exp2f(y0[k]);
            d1[k] = __builtin_amdgcn_exp2f(y1[k]);
        }
        // Phase 3: all +1 (full-rate, overlaps exp drain)
        #pragma unroll
        for (int k = 0; k < KPT; ++k) {
            d0[k] += 1.0f;
            d1[k] += 1.0f;
        }
        // Phase 4: all 16 rcps + fused update u' = 0.5*y + C*(0.5 - r)
        #pragma unroll
        for (int k = 0; k < KPT; ++k) {
            float r0 = __builtin_amdgcn_rcpf(d0[k]);
            float r1 = __builtin_amdgcn_rcpf(d1[k]);
            u0[k] = fmaf(-C, r0, fmaf(0.5f, y0[k], halfC));
            u1[k] = fmaf(-C, r1, fmaf(0.5f, y1[k], halfC));
        }
        w = wn; b = bn;
    }

    // Final linear + L2 normalize (uniform scale C cancels in normalization).
    const float g0 = fW[0], g1 = fW[1], g2 = fW[2], g3 = fW[3];

    #pragma unroll
    for (int j = 0; j < KPT / 2; ++j) {
        if (!ok[j]) continue;
        float4 o;
        #pragma unroll
        for (int h = 0; h < 2; ++h) {
            const int k = 2 * j + h;
            float z0 = fmaf(g0, u0[k], g1 * u1[k]);
            float z1 = fmaf(g2, u0[k], g3 * u1[k]);
            float s  = fmaf(z0, z0, z1 * z1);
            float n  = __builtin_amdgcn_sqrtf(s);
            float iv = __builtin_amdgcn_rcpf(fmaxf(n, 1e-12f));
            if (h == 0) { o.x = z0 * iv; o.y = z1 * iv; }
            else        { o.z = z0 * iv; o.w = z1 * iv; }
        }
        out4[idx[j]] = o;
    }
}

extern "C" void kernel_launch(void* const* d_in, const int* in_sizes, int n_in,
                              void* d_out, int out_size, void* d_ws, size_t ws_size,
                              hipStream_t stream) {
    // 0=T(unused), 1=closed_manifold [N,2], 2=Ws [L,2,2], 3=bs [L,2], 4=final_W [2,2]
    const float* X  = (const float*)d_in[1];
    const float* Ws = (const float*)d_in[2];
    const float* bs = (const float*)d_in[3];
    const float* fW = (const float*)d_in[4];
    float* out = (float*)d_out;

    const int L = in_sizes[2] / 4;
    const int M = in_sizes[1] / 4;
    const int threads = (M + (KPT / 2) - 1) / (KPT / 2);
    const int grid = (threads + BLOCK - 1) / BLOCK;

    nig_kernel<<<grid, BLOCK, 0, stream>>>(X, Ws, bs, fW, out, M, L);
}